// Round 4
// baseline (601.843 us; speedup 1.0000x reference)
//
#include <hip/hip_runtime.h>
#include <math.h>

#define B  64
#define H  4
#define NN 16384
#define WD 64
#define DD 1024
#define PP 70   // W + 6

typedef float fx4 __attribute__((ext_vector_type(4)));  // native vec for nontemporal builtins

__device__ __forceinline__ float softplus_f(float x) {
    return fmaxf(x, 0.f) + log1pf(expf(-fabsf(x)));
}

// ---------------------------------------------------------------------------
// Kernel 1: params = state @ W_read.T + b_read, then activations.
// One block per (b,h). Outputs: kscaled[bh][64] = key * beta/max(||key||,eps),
// coef[bh][8] = {gate, sh0, sh1, sh2, gamma, beta}. Also zeroes sums[bh]
// (d_ws is re-poisoned 0xAA before every launch).
// ---------------------------------------------------------------------------
__global__ __launch_bounds__(256) void k_params(
    const float* __restrict__ state, const float* __restrict__ Wr,
    const float* __restrict__ br, float* __restrict__ kscaled,
    float* __restrict__ coef, float* __restrict__ sums)
{
    int bh = blockIdx.x;           // b*4 + h
    int b  = bh >> 2, h = bh & 3;
    int tid = threadIdx.x, wave = tid >> 6, lane = tid & 63;
    __shared__ float sp[PP];
    __shared__ float sbc[1];

    const float4* st4 = (const float4*)(state + (size_t)b * DD);
    for (int j = wave; j < PP; j += 4) {
        const float4* w4 = (const float4*)(Wr + (size_t)(h * PP + j) * DD);
        float acc = 0.f;
        #pragma unroll
        for (int q = 0; q < 4; ++q) {
            float4 wv = w4[lane + 64 * q];
            float4 sv = st4[lane + 64 * q];
            acc += wv.x * sv.x + wv.y * sv.y + wv.z * sv.z + wv.w * sv.w;
        }
        #pragma unroll
        for (int m = 32; m >= 1; m >>= 1) acc += __shfl_xor(acc, m, 64);
        if (lane == 0) sp[j] = acc + br[h * PP + j];
    }
    __syncthreads();
    if (tid == 0) {
        float ss = 0.f;
        for (int w = 0; w < WD; ++w) ss += sp[w] * sp[w];
        float knorm = fmaxf(sqrtf(ss), 1e-8f);
        float beta  = softplus_f(sp[64]);
        float gate  = 1.f / (1.f + expf(-sp[65]));
        float m3 = fmaxf(sp[66], fmaxf(sp[67], sp[68]));
        float e0 = expf(sp[66] - m3), e1 = expf(sp[67] - m3), e2 = expf(sp[68] - m3);
        float es = e0 + e1 + e2;
        float gamma = 1.f + softplus_f(sp[69]);
        float* c = coef + bh * 8;
        c[0] = gate; c[1] = e0 / es; c[2] = e1 / es; c[3] = e2 / es;
        c[4] = gamma; c[5] = beta;
        sums[bh] = 0.f;            // zero the atomic accumulator for k_sim
        sbc[0] = beta / knorm;
    }
    __syncthreads();
    if (tid < WD) kscaled[bh * WD + tid] = sp[tid] * sbc[0];
}

// ---------------------------------------------------------------------------
// Kernel 2: e[b][h][n] = exp(beta*(cos_sim - 1))  [softmax numerator shifted
// by the a-priori bound s<=beta], plus atomic per-(b,h) denominator sums.
// Wave handles 8 rows/iter: r=lane>>3, c=lane&7; lane owns 8 cols of one row.
// ---------------------------------------------------------------------------
__global__ __launch_bounds__(256) void k_sim(
    const float* __restrict__ mem, const float* __restrict__ kscaled,
    const float* __restrict__ coef, float* __restrict__ ebuf,
    float* __restrict__ sums)
{
    int tid = threadIdx.x, wave = tid >> 6, lane = tid & 63;
    int blk = blockIdx.x;              // 16384 blocks
    int b = blk >> 8;                  // 256 blocks per batch
    int nblk = (blk & 255) * 64;       // 64 rows per block
    int r = lane >> 3, c = lane & 7;   // 8 rows x 8 col-groups

    const float* ksb = kscaled + b * 4 * WD + c * 8;
    float4 k0a = *(const float4*)(ksb + 0 * WD);
    float4 k0b = *(const float4*)(ksb + 0 * WD + 4);
    float4 k1a = *(const float4*)(ksb + 1 * WD);
    float4 k1b = *(const float4*)(ksb + 1 * WD + 4);
    float4 k2a = *(const float4*)(ksb + 2 * WD);
    float4 k2b = *(const float4*)(ksb + 2 * WD + 4);
    float4 k3a = *(const float4*)(ksb + 3 * WD);
    float4 k3b = *(const float4*)(ksb + 3 * WD + 4);

    float bet = (c < 4) ? coef[(b * 4 + c) * 8 + 5] : 0.f;
    float psum = 0.f;

    int nw = nblk + wave * 16;
    #pragma unroll
    for (int it = 0; it < 2; ++it) {
        int n = nw + it * 8 + r;
        const fx4* rp = (const fx4*)(mem + ((size_t)b * NN + n) * WD + c * 8);
        fx4 v0 = __builtin_nontemporal_load(rp);
        fx4 v1 = __builtin_nontemporal_load(rp + 1);
        float d0 = v0.x*k0a.x + v0.y*k0a.y + v0.z*k0a.z + v0.w*k0a.w
                 + v1.x*k0b.x + v1.y*k0b.y + v1.z*k0b.z + v1.w*k0b.w;
        float d1 = v0.x*k1a.x + v0.y*k1a.y + v0.z*k1a.z + v0.w*k1a.w
                 + v1.x*k1b.x + v1.y*k1b.y + v1.z*k1b.z + v1.w*k1b.w;
        float d2 = v0.x*k2a.x + v0.y*k2a.y + v0.z*k2a.z + v0.w*k2a.w
                 + v1.x*k2b.x + v1.y*k2b.y + v1.z*k2b.z + v1.w*k2b.w;
        float d3 = v0.x*k3a.x + v0.y*k3a.y + v0.z*k3a.z + v0.w*k3a.w
                 + v1.x*k3b.x + v1.y*k3b.y + v1.z*k3b.z + v1.w*k3b.w;
        float q  = v0.x*v0.x + v0.y*v0.y + v0.z*v0.z + v0.w*v0.w
                 + v1.x*v1.x + v1.y*v1.y + v1.z*v1.z + v1.w*v1.w;
        #pragma unroll
        for (int m = 1; m < 8; m <<= 1) {
            d0 += __shfl_xor(d0, m, 64);
            d1 += __shfl_xor(d1, m, 64);
            d2 += __shfl_xor(d2, m, 64);
            d3 += __shfl_xor(d3, m, 64);
            q  += __shfl_xor(q,  m, 64);
        }
        if (c < 4) {
            float mn = fmaxf(sqrtf(q), 1e-8f);
            float d  = (c == 0) ? d0 : ((c == 1) ? d1 : ((c == 2) ? d2 : d3));
            float e  = __expf(d / mn - bet);   // s - beta in [-2beta, 0]
            ebuf[((size_t)(b * 4 + c)) * NN + n] = e;
            psum += e;
        }
    }
    // reduce psum over the 8 r-groups (lane bits 3..5), then one atomic per h
    #pragma unroll
    for (int m = 8; m < 64; m <<= 1) psum += __shfl_xor(psum, m, 64);
    if (r == 0 && c < 4) atomicAdd(&sums[b * 4 + c], psum);
}

// ---------------------------------------------------------------------------
// Kernel 3: per (b,h) row: normalize (denominator precomputed), gate-mix,
// circular 3-tap shift, sharpen, renormalize. One block (1024 thr) per row.
// No softmax max/sum phases remain — single block reduction at the end.
// ---------------------------------------------------------------------------
__global__ __launch_bounds__(1024) void k_head(
    const float* __restrict__ ebuf, const float* __restrict__ prev,
    const float* __restrict__ coef, const float* __restrict__ sums,
    float* __restrict__ out)
{
    __shared__ float lds[NN];   // exactly 64 KiB
    int bh = blockIdx.x;
    int tid = threadIdx.x, wave = tid >> 6, lane = tid & 63;
    const float* erow = ebuf + (size_t)bh * NN;
    const float* prow = prev + (size_t)bh * NN;
    float* orow = out + (size_t)bh * NN;
    const float* c = coef + bh * 8;
    float gate = c[0], sh0 = c[1], sh1 = c[2], sh2 = c[3], gamma = c[4];
    float ginvS = gate / sums[bh];
    float omg   = 1.f - gate;

    #pragma unroll
    for (int k = 0; k < 16; ++k) {
        int n = tid + k * 1024;
        lds[n] = ginvS * erow[n] + omg * prow[n];
    }
    __syncthreads();
    // ---- shift + sharpen ----
    float sh[16];
    float ps = 0.f;
    #pragma unroll
    for (int k = 0; k < 16; ++k) {
        int n = tid + k * 1024;
        float gm1 = lds[(n + NN - 1) & (NN - 1)];
        float g0  = lds[n];
        float gp1 = lds[(n + 1) & (NN - 1)];
        float val = sh0 * gm1 + sh1 * g0 + sh2 * gp1;
        sh[k] = __expf(gamma * __logf(val));   // val > 0 strictly
        ps += sh[k];
    }
    __syncthreads();   // all LDS reads done before reduction reuses lds[0..16]
    #pragma unroll
    for (int d = 32; d >= 1; d >>= 1) ps += __shfl_xor(ps, d, 64);
    if (lane == 0) lds[wave] = ps;
    __syncthreads();
    if (tid == 0) {
        float x = 0.f;
        for (int i = 0; i < 16; ++i) x += lds[i];
        lds[16] = x;
    }
    __syncthreads();
    float T = lds[16] + 1e-6f;
    float invT = 1.f / T;
    #pragma unroll
    for (int k = 0; k < 16; ++k) orow[tid + k * 1024] = sh[k] * invT;
}

// ---------------------------------------------------------------------------
extern "C" void kernel_launch(void* const* d_in, const int* in_sizes, int n_in,
                              void* d_out, int out_size, void* d_ws, size_t ws_size,
                              hipStream_t stream) {
    const float* state = (const float*)d_in[0];   // (B, D)
    const float* prev  = (const float*)d_in[1];   // (B, H, N)
    const float* mem   = (const float*)d_in[2];   // (B, N, W)
    const float* Wr    = (const float*)d_in[3];   // (P*H, D)
    const float* br    = (const float*)d_in[4];   // (P*H,)
    float* out = (float*)d_out;                   // (B, H, N)

    float* ebuf    = (float*)d_ws;                     // B*H*N floats = 16 MB
    float* kscaled = ebuf + (size_t)B * H * NN;        // B*H*64 floats
    float* coef    = kscaled + (size_t)B * H * WD;     // B*H*8 floats
    float* sums    = coef + (size_t)B * H * 8;         // B*H floats

    k_params<<<B * H, 256, 0, stream>>>(state, Wr, br, kscaled, coef, sums);
    k_sim<<<(B * NN) / 64, 256, 0, stream>>>(mem, kscaled, coef, ebuf, sums);
    k_head<<<B * H, 1024, 0, stream>>>(ebuf, prev, coef, sums, out);
}

// Round 5
// 391.873 us; speedup vs baseline: 1.5358x; 1.5358x over previous
//
#include <hip/hip_runtime.h>
#include <math.h>

#define B  64
#define H  4
#define NN 16384
#define WD 64
#define DD 1024
#define PP 70   // W + 6

typedef float fx4 __attribute__((ext_vector_type(4)));  // native vec for nontemporal builtins

__device__ __forceinline__ float softplus_f(float x) {
    return fmaxf(x, 0.f) + log1pf(expf(-fabsf(x)));
}

// ---------------------------------------------------------------------------
// Kernel 1: params = state @ W_read.T + b_read, then activations.
// One block per (b,h). Outputs: kscaled[bh][64] = key * beta/max(||key||,eps),
// coef[bh][8] = {gate, sh0, sh1, sh2, gamma, beta}.
// ---------------------------------------------------------------------------
__global__ __launch_bounds__(256) void k_params(
    const float* __restrict__ state, const float* __restrict__ Wr,
    const float* __restrict__ br, float* __restrict__ kscaled,
    float* __restrict__ coef)
{
    int bh = blockIdx.x;           // b*4 + h
    int b  = bh >> 2, h = bh & 3;
    int tid = threadIdx.x, wave = tid >> 6, lane = tid & 63;
    __shared__ float sp[PP];
    __shared__ float sbc[1];

    const float4* st4 = (const float4*)(state + (size_t)b * DD);
    for (int j = wave; j < PP; j += 4) {
        const float4* w4 = (const float4*)(Wr + (size_t)(h * PP + j) * DD);
        float acc = 0.f;
        #pragma unroll
        for (int q = 0; q < 4; ++q) {
            float4 wv = w4[lane + 64 * q];
            float4 sv = st4[lane + 64 * q];
            acc += wv.x * sv.x + wv.y * sv.y + wv.z * sv.z + wv.w * sv.w;
        }
        #pragma unroll
        for (int m = 32; m >= 1; m >>= 1) acc += __shfl_xor(acc, m, 64);
        if (lane == 0) sp[j] = acc + br[h * PP + j];
    }
    __syncthreads();
    if (tid == 0) {
        float ss = 0.f;
        for (int w = 0; w < WD; ++w) ss += sp[w] * sp[w];
        float knorm = fmaxf(sqrtf(ss), 1e-8f);
        float beta  = softplus_f(sp[64]);
        float gate  = 1.f / (1.f + expf(-sp[65]));
        float m3 = fmaxf(sp[66], fmaxf(sp[67], sp[68]));
        float e0 = expf(sp[66] - m3), e1 = expf(sp[67] - m3), e2 = expf(sp[68] - m3);
        float es = e0 + e1 + e2;
        float gamma = 1.f + softplus_f(sp[69]);
        float* c = coef + bh * 8;
        c[0] = gate; c[1] = e0 / es; c[2] = e1 / es; c[3] = e2 / es;
        c[4] = gamma; c[5] = beta;
        sbc[0] = beta / knorm;
    }
    __syncthreads();
    if (tid < WD) kscaled[bh * WD + tid] = sp[tid] * sbc[0];
}

// ---------------------------------------------------------------------------
// Kernel 2: e[b][h][n] = exp(beta*cos_sim - beta)  (softmax numerator shifted
// by the a-priori bound s<=beta; denominator recomputed in k_head).
// 128 rows/block, 32 rows/wave, 4 iters; ALL 8 loads issued up-front for MLP.
// Lane r=lane>>3 owns row, c=lane&7 owns 8 columns; 8-lane xor reductions.
// NO atomics (R4's 256-address atomic fan-in serialized the whole kernel).
// ---------------------------------------------------------------------------
__global__ __launch_bounds__(256) void k_sim(
    const float* __restrict__ mem, const float* __restrict__ kscaled,
    const float* __restrict__ coef, float* __restrict__ ebuf)
{
    int tid = threadIdx.x, wave = tid >> 6, lane = tid & 63;
    int blk = blockIdx.x;              // 8192 blocks
    int b = blk >> 7;                  // 128 blocks per batch
    int nblk = (blk & 127) * 128;      // 128 rows per block
    int r = lane >> 3, c = lane & 7;   // 8 rows x 8 col-groups

    const float* ksb = kscaled + b * 4 * WD + c * 8;
    float4 k0a = *(const float4*)(ksb + 0 * WD);
    float4 k0b = *(const float4*)(ksb + 0 * WD + 4);
    float4 k1a = *(const float4*)(ksb + 1 * WD);
    float4 k1b = *(const float4*)(ksb + 1 * WD + 4);
    float4 k2a = *(const float4*)(ksb + 2 * WD);
    float4 k2b = *(const float4*)(ksb + 2 * WD + 4);
    float4 k3a = *(const float4*)(ksb + 3 * WD);
    float4 k3b = *(const float4*)(ksb + 3 * WD + 4);

    float bet = (c < 4) ? coef[(b * 4 + c) * 8 + 5] : 0.f;

    int nw = nblk + wave * 32;
    // issue all 8 loads before any dependent compute (MLP)
    fx4 va[4], vb[4];
    #pragma unroll
    for (int it = 0; it < 4; ++it) {
        int n = nw + it * 8 + r;
        const fx4* rp = (const fx4*)(mem + ((size_t)b * NN + n) * WD + c * 8);
        va[it] = __builtin_nontemporal_load(rp);
        vb[it] = __builtin_nontemporal_load(rp + 1);
    }
    #pragma unroll
    for (int it = 0; it < 4; ++it) {
        fx4 v0 = va[it], v1 = vb[it];
        int n = nw + it * 8 + r;
        float d0 = v0.x*k0a.x + v0.y*k0a.y + v0.z*k0a.z + v0.w*k0a.w
                 + v1.x*k0b.x + v1.y*k0b.y + v1.z*k0b.z + v1.w*k0b.w;
        float d1 = v0.x*k1a.x + v0.y*k1a.y + v0.z*k1a.z + v0.w*k1a.w
                 + v1.x*k1b.x + v1.y*k1b.y + v1.z*k1b.z + v1.w*k1b.w;
        float d2 = v0.x*k2a.x + v0.y*k2a.y + v0.z*k2a.z + v0.w*k2a.w
                 + v1.x*k2b.x + v1.y*k2b.y + v1.z*k2b.z + v1.w*k2b.w;
        float d3 = v0.x*k3a.x + v0.y*k3a.y + v0.z*k3a.z + v0.w*k3a.w
                 + v1.x*k3b.x + v1.y*k3b.y + v1.z*k3b.z + v1.w*k3b.w;
        float q  = v0.x*v0.x + v0.y*v0.y + v0.z*v0.z + v0.w*v0.w
                 + v1.x*v1.x + v1.y*v1.y + v1.z*v1.z + v1.w*v1.w;
        #pragma unroll
        for (int m = 1; m < 8; m <<= 1) {
            d0 += __shfl_xor(d0, m, 64);
            d1 += __shfl_xor(d1, m, 64);
            d2 += __shfl_xor(d2, m, 64);
            d3 += __shfl_xor(d3, m, 64);
            q  += __shfl_xor(q,  m, 64);
        }
        if (c < 4) {
            float mn = fmaxf(sqrtf(q), 1e-8f);
            float d  = (c == 0) ? d0 : ((c == 1) ? d1 : ((c == 2) ? d2 : d3));
            ebuf[((size_t)(b * 4 + c)) * NN + n] = __expf(d / mn - bet);
        }
    }
}

// ---------------------------------------------------------------------------
// Kernel 3: per (b,h) row: block-reduce denominator S, normalize, gate-mix,
// circular 3-tap shift, sharpen, renormalize. One block (1024 thr) per row.
// ---------------------------------------------------------------------------
__global__ __launch_bounds__(1024) void k_head(
    const float* __restrict__ ebuf, const float* __restrict__ prev,
    const float* __restrict__ coef, float* __restrict__ out)
{
    __shared__ float lds[NN];   // exactly 64 KiB
    int bh = blockIdx.x;
    int tid = threadIdx.x, wave = tid >> 6, lane = tid & 63;
    const float* erow = ebuf + (size_t)bh * NN;
    const float* prow = prev + (size_t)bh * NN;
    float* orow = out + (size_t)bh * NN;
    const float* c = coef + bh * 8;
    float gate = c[0], sh0 = c[1], sh1 = c[2], sh2 = c[3], gamma = c[4];

    float ev[16], pw[16];
    float ls = 0.f;
    #pragma unroll
    for (int k = 0; k < 16; ++k) {
        int n = tid + k * 1024;
        ev[k] = erow[n];
        pw[k] = prow[n];
        ls += ev[k];
    }
    #pragma unroll
    for (int d = 32; d >= 1; d >>= 1) ls += __shfl_xor(ls, d, 64);
    if (lane == 0) lds[wave] = ls;
    __syncthreads();
    if (tid == 0) {
        float x = 0.f;
        for (int i = 0; i < 16; ++i) x += lds[i];
        lds[16] = x;
    }
    __syncthreads();
    float S = lds[16];
    __syncthreads();
    float ginvS = gate / S;
    float omg   = 1.f - gate;

    #pragma unroll
    for (int k = 0; k < 16; ++k) {
        int n = tid + k * 1024;
        lds[n] = ginvS * ev[k] + omg * pw[k];
    }
    __syncthreads();
    // ---- shift + sharpen ----
    float sh[16];
    float ps = 0.f;
    #pragma unroll
    for (int k = 0; k < 16; ++k) {
        int n = tid + k * 1024;
        float gm1 = lds[(n + NN - 1) & (NN - 1)];
        float g0  = lds[n];
        float gp1 = lds[(n + 1) & (NN - 1)];
        float val = sh0 * gm1 + sh1 * g0 + sh2 * gp1;
        sh[k] = __expf(gamma * __logf(val));   // val > 0 strictly
        ps += sh[k];
    }
    __syncthreads();   // all LDS reads done before reduction reuses lds[0..16]
    #pragma unroll
    for (int d = 32; d >= 1; d >>= 1) ps += __shfl_xor(ps, d, 64);
    if (lane == 0) lds[wave] = ps;
    __syncthreads();
    if (tid == 0) {
        float x = 0.f;
        for (int i = 0; i < 16; ++i) x += lds[i];
        lds[16] = x;
    }
    __syncthreads();
    float T = lds[16] + 1e-6f;
    float invT = 1.f / T;
    #pragma unroll
    for (int k = 0; k < 16; ++k) orow[tid + k * 1024] = sh[k] * invT;
}

// ---------------------------------------------------------------------------
extern "C" void kernel_launch(void* const* d_in, const int* in_sizes, int n_in,
                              void* d_out, int out_size, void* d_ws, size_t ws_size,
                              hipStream_t stream) {
    const float* state = (const float*)d_in[0];   // (B, D)
    const float* prev  = (const float*)d_in[1];   // (B, H, N)
    const float* mem   = (const float*)d_in[2];   // (B, N, W)
    const float* Wr    = (const float*)d_in[3];   // (P*H, D)
    const float* br    = (const float*)d_in[4];   // (P*H,)
    float* out = (float*)d_out;                   // (B, H, N)

    float* ebuf    = (float*)d_ws;                     // B*H*N floats = 16 MB
    float* kscaled = ebuf + (size_t)B * H * NN;        // B*H*64 floats
    float* coef    = kscaled + (size_t)B * H * WD;     // B*H*8 floats

    k_params<<<B * H, 256, 0, stream>>>(state, Wr, br, kscaled, coef);
    k_sim<<<(B * NN) / 128, 256, 0, stream>>>(mem, kscaled, coef, ebuf);
    k_head<<<B * H, 1024, 0, stream>>>(ebuf, prev, coef, out);
}